// Round 5
// baseline (826.087 us; speedup 1.0000x reference)
//
#include <hip/hip_runtime.h>
#include <hip/hip_bf16.h>

// Problem constants
#define NN 32768      // nodes
#define BB 1024       // graphs
#define PP 32         // nodes per graph
#define EE 65536      // edges
#define HH 768
#define KSEM 1024
#define KCAT 1536
#define KP1 4608

typedef __attribute__((ext_vector_type(8))) short bf16x8;
typedef __attribute__((ext_vector_type(4))) float f32x4;

__device__ __forceinline__ unsigned short f2bf(float f){
  union { float f; unsigned u; } v; v.f = f;
  unsigned r = v.u + 0x7FFFu + ((v.u >> 16) & 1u);
  return (unsigned short)(r >> 16);
}
__device__ __forceinline__ float bf2f(unsigned short u){
  union { unsigned u; float f; } v; v.u = ((unsigned)u) << 16; return v.f;
}

__device__ __forceinline__ void gld_lds16(const void* g, void* l){
  __builtin_amdgcn_global_load_lds(
      (const __attribute__((address_space(1))) unsigned int*)g,
      (__attribute__((address_space(3))) unsigned int*)l, 16, 0, 0);
}

// ---------------- f32 -> bf16 cast, 8 elems/thread
__global__ __launch_bounds__(256) void k_cast(const float* __restrict__ in,
                                              unsigned short* __restrict__ out, int n8){
  int i = blockIdx.x * 256 + threadIdx.x;
  if (i >= n8) return;
  const float4* p = (const float4*)(in + (size_t)i * 8);
  float4 u0 = p[0], u1 = p[1];
  unsigned short vv[8];
  vv[0]=f2bf(u0.x); vv[1]=f2bf(u0.y); vv[2]=f2bf(u0.z); vv[3]=f2bf(u0.w);
  vv[4]=f2bf(u1.x); vv[5]=f2bf(u1.y); vv[6]=f2bf(u1.z); vv[7]=f2bf(u1.w);
  *(bf16x8*)(out + (size_t)i * 8) = *(bf16x8*)vv;
}

// ---------------- weight transpose: in (Kin x 768) f32 -> out[n*ostride + ooff + k] bf16
__global__ void k_transpose(const float* __restrict__ in, unsigned short* __restrict__ out,
                            int Kin, int ostride, int ooff){
  __shared__ float tile[32][33];
  int kb = blockIdx.x * 32, nb = blockIdx.y * 32;
  int tx = threadIdx.x & 31, ty = threadIdx.x >> 5; // 32 x 8
  #pragma unroll
  for (int i = ty; i < 32; i += 8)
    tile[i][tx] = in[(size_t)(kb + i) * 768 + nb + tx];
  __syncthreads();
  #pragma unroll
  for (int i = ty; i < 32; i += 8)
    out[(size_t)(nb + i) * ostride + ooff + kb + tx] = f2bf(tile[tx][i]);
}

// ================= 256x128 pipelined GEMM, 2 phases/K-tile, counted vmcnt(2) =================
// C(M x 768) = A(M x K) @ B; A bf16 row-major [M][K], Bt = [768][K] bf16.
// 512 threads = 8 waves (4M x 2N); per-wave output 64x64; BK=64.
// LDS 96KB: A dbuf 2x32KB @0, B dbuf 2x16KB @65536.
// Swizzle (G4): byte_in_row ^= (row&7)<<4, pre-swizzled on the global staging
// source (rule 21) and applied on ds_read -> all 32 banks, 2-way (free).
// Pipeline: per tile t: ph1 {LDA q0 + LDB + STG_A(t+1)} ph2 {LDA q1 + STG_B(t+2)};
// vmcnt(2) once per tile (leaves B(t+2)'s 2 loads in flight; never drains to 0).
// EPI 0: h_text = relu(acc + spk+emo) -> h f32, htext bf16
// EPI 1: h = relu(acc) + h (in place f32)
// MSG 1: epilogue also computes per-graph segment-sum from the bf16 h tile in LDS
//        and writes acat_next[row] = [bf16(h) | bf16(msg)] for this col range.

#define BAR __builtin_amdgcn_s_barrier()
#define WAITL asm volatile("s_waitcnt lgkmcnt(0)" ::: "memory")
#define WAITV2 asm volatile("s_waitcnt vmcnt(2)" ::: "memory")
#define WAITV0 asm volatile("s_waitcnt vmcnt(0)" ::: "memory")

#define STG_A(buf,tile) { _Pragma("unroll") for (int i_=0;i_<4;++i_) \
    gld_lds16(aS + (size_t)(i_*64)*K + (size_t)(tile)*64, dst0 + (buf)*16384 + i_*4096); }
#define STG_B(buf,tile) { _Pragma("unroll") for (int i_=0;i_<2;++i_) \
    gld_lds16(bS + (size_t)(i_*64)*K + (size_t)(tile)*64, dst0 + 32768 + (buf)*8192 + i_*4096); }
#define LDA(buf,q) { _Pragma("unroll") for (int jj=0;jj<2;++jj){ \
    const int R_ = wrow*64 + ((q)*2+jj)*16 + l15; const int sw_ = (R_&7)<<4; \
    const char* p_ = (const char*)LDSB + (buf)*32768 + R_*128; \
    af[jj][0] = *(const bf16x8*)(p_ + (kq ^ sw_)); \
    af[jj][1] = *(const bf16x8*)(p_ + ((64|kq) ^ sw_)); }}
#define LDB(buf) { _Pragma("unroll") for (int nn=0;nn<4;++nn){ \
    const int R_ = wcol*64 + nn*16 + l15; const int sw_ = (R_&7)<<4; \
    const char* p_ = (const char*)LDSB + 65536 + (buf)*16384 + R_*128; \
    bfr[nn][0] = *(const bf16x8*)(p_ + (kq ^ sw_)); \
    bfr[nn][1] = *(const bf16x8*)(p_ + ((64|kq) ^ sw_)); }}
#define MMA2(q) { __builtin_amdgcn_s_setprio(1); \
    _Pragma("unroll") for (int jj=0;jj<2;++jj) _Pragma("unroll") for (int nn=0;nn<4;++nn){ \
      acc[(q)*2+jj][nn] = __builtin_amdgcn_mfma_f32_16x16x32_bf16(af[jj][0], bfr[nn][0], acc[(q)*2+jj][nn],0,0,0); \
      acc[(q)*2+jj][nn] = __builtin_amdgcn_mfma_f32_16x16x32_bf16(af[jj][1], bfr[nn][1], acc[(q)*2+jj][nn],0,0,0); } \
    __builtin_amdgcn_s_setprio(0); }

template<int EPI, int MSG>
__global__ __launch_bounds__(512, 2) void k_gemm8(
    const unsigned short* __restrict__ A, const unsigned short* __restrict__ Bt, int K,
    float* __restrict__ h, unsigned short* __restrict__ htext,
    const int* __restrict__ sid, const int* __restrict__ eid,
    const float* __restrict__ spk, const float* __restrict__ emo,
    const int* __restrict__ esrc, const int* __restrict__ etgt,
    unsigned short* __restrict__ acat)
{
  __shared__ __align__(16) unsigned char LDSB[98304];
  unsigned short* LDSu = (unsigned short*)LDSB;
  const int t = threadIdx.x;
  const int lane = t & 63, w = t >> 6;
  const int wrow = w >> 1, wcol = w & 1;

  // bijective XCD-chunked swizzle (gridDim.x % 8 == 0), col-fastest (6 col panels)
  const int bid = blockIdx.x;
  const int cpx = gridDim.x >> 3;
  const int wg = (bid & 7) * cpx + (bid >> 3);
  const int by = wg / 6, bx = wg - by * 6;
  const int brow = by * 256, bcol = bx * 128;

  f32x4 acc[4][4];
  #pragma unroll
  for (int m = 0; m < 4; ++m)
    #pragma unroll
    for (int n = 0; n < 4; ++n) acc[m][n] = f32x4{0.f,0.f,0.f,0.f};

  // staging: thread t covers LDS row (t>>3) of each 64-row issue, col bytes (t&7)*16,
  // source column pre-swizzled by ((row&7)<<4) so linear LDS ends up swizzled.
  const int srow = t >> 3;
  const int scol = ((t & 7) ^ ((t >> 3) & 7)) * 8;
  const unsigned short* aS = A  + (size_t)(brow + srow) * K + scol;
  const unsigned short* bS = Bt + (size_t)(bcol + srow) * K + scol;
  unsigned short* dst0 = LDSu + w * 512;
  const int l15 = lane & 15, kq = (lane >> 4) * 16;  // kq = byte offset of k-group
  const int nkt = K >> 6;

  bf16x8 af[2][2], bfr[4][2];

  // prologue: A(0), B(0), B(1); wait A(0)+B(0) landed, B(1)'s 2 loads fly
  STG_A(0,0); STG_B(0,0); STG_B(1,1);
  WAITV2; BAR;

  for (int t0 = 0; t0 < nkt; ++t0){
    const int ab = t0 & 1;
    const int t1 = (t0+1 < nkt) ? t0+1 : nkt-1;   // tail: harmless refetch, data unused
    const int t2 = (t0+2 < nkt) ? t0+2 : nkt-1;
    // ph1: A-buf[ab^1] was fully consumed in tile t0-1 ph2 (barriered) -> safe to stage
    LDA(ab,0); LDB(ab); STG_A(ab^1, t1);
    BAR; WAITL; MMA2(0); BAR;
    // ph2: B-buf[ab] was fully consumed in ph1 (barriered) -> stage B(t0+2) into it
    LDA(ab,1); STG_B(ab, t2);
    BAR; WAITL; MMA2(1);
    WAITV2; BAR;   // A(t1) + B(t1) landed; B(t2)'s 2 loads may fly
  }
  WAITV0;          // drain tail prefetches (LDS about to be reused as hs)
  __syncthreads();

  // epilogue: C/D layout col=lane&15, row=(lane>>4)*4+reg
  unsigned short* hs = LDSu;   // [256][128] bf16 h-tile (64KB, A-buf region)
  #pragma unroll
  for (int m = 0; m < 4; ++m){
    #pragma unroll
    for (int n = 0; n < 4; ++n){
      const int col_l = wcol*64 + n*16 + l15;
      const int col = bcol + col_l;
      #pragma unroll
      for (int j = 0; j < 4; ++j){
        const int row_l = wrow*64 + m*16 + ((lane>>4)*4) + j;
        const int row = brow + row_l;
        float v = acc[m][n][j];
        if (EPI == 0){
          float e = spk[sid[row] * 768 + col] + emo[eid[row] * 768 + col];
          v = fmaxf(v + e, 0.f);
          h[(size_t)row * 768 + col] = v;
          htext[(size_t)row * 768 + col] = f2bf(v);
        } else {
          v = fmaxf(v, 0.f) + h[(size_t)row * 768 + col];
          h[(size_t)row * 768 + col] = v;
        }
        if (MSG) hs[row_l * 128 + col_l] = f2bf(v);
      }
    }
  }

  if (MSG){
    // segment-sum for the block's 8 complete graphs, cols [bcol, bcol+128)
    __syncthreads();
    int* cnt = (int*)(LDSB + 65536);            // [256]
    unsigned char* lst = LDSB + 66560;          // [256][64]
    if (t < 256) cnt[t] = 0;
    __syncthreads();
    {
      const int gl = t >> 6, e = t & 63;        // 8 graphs x 64 edges = 512 threads
      const int ge = (by*8 + gl)*64 + e;
      const int s  = esrc[ge] & 31;             // intra-graph local ids
      const int tg = etgt[ge] & 31;
      const int slot = atomicAdd(&cnt[gl*32 + tg], 1);
      lst[(gl*32 + tg)*64 + slot] = (unsigned char)s;
    }
    __syncthreads();
    const int col = t & 127;
    for (int r = t >> 7; r < 256; r += 4){
      const int gbase = (r & ~31) * 128 + col;  // graph-start row in hs
      const int c = cnt[r];
      float s = 0.f;
      for (int e = 0; e < c; ++e)
        s += bf2f(hs[gbase + ((int)lst[r*64 + e])*128]);
      const size_t grow = (size_t)(brow + r) * 1536;
      acat[grow + bcol + col]       = hs[r*128 + col];
      acat[grow + 768 + bcol + col] = f2bf(s);
    }
  }
}

// ================= 128x128 m97-style GEMM for the small (M=1024) shapes =================
// EPI 2: z = relu(acc + bias) -> obf at col base 3840, stride 4608 (edge_repr)
// EPI 3: hid = relu(acc + bias) -> of32 stride 768
template<int EPI>
__global__ __launch_bounds__(256) void k_gemm(
    const unsigned short* __restrict__ A, const unsigned short* __restrict__ Bt, int K,
    const float* __restrict__ bias,
    unsigned short* __restrict__ obf, float* __restrict__ of32)
{
  __shared__ unsigned short As[128*64];
  __shared__ unsigned short Bs[128*64];
  const int t = threadIdx.x;
  const int lane = t & 63, wave = t >> 6;

  const int bid = blockIdx.x;
  const int cpx = gridDim.x >> 3;
  const int wg = (bid & 7) * cpx + (bid >> 3);
  const int by = wg / 6;
  const int bx = wg - by * 6;
  const int brow = by * 128;
  const int bcol = bx * 128;

  const int wr = (wave >> 1) * 64, wc = (wave & 1) * 64;

  f32x4 acc[4][4];
  #pragma unroll
  for (int m = 0; m < 4; ++m)
    #pragma unroll
    for (int n = 0; n < 4; ++n)
      acc[m][n] = f32x4{0.f, 0.f, 0.f, 0.f};

  const int srow = wave * 8 + (lane >> 3);
  const int scol = (lane & 7) * 8;
  const int nkt = K >> 6;

  const unsigned short* a0 = A  + (size_t)(brow + srow) * K + scol;
  const unsigned short* b0 = Bt + (size_t)(bcol + srow) * K + scol;
  unsigned short* asdst = As + wave * 512;
  unsigned short* bsdst = Bs + wave * 512;

  for (int kt = 0; kt < nkt; ++kt){
    const unsigned short* ak = a0 + kt * 64;
    const unsigned short* bk = b0 + kt * 64;
    #pragma unroll
    for (int i = 0; i < 4; ++i)
      gld_lds16(ak + (size_t)i * 32 * K, asdst + i * 2048);
    #pragma unroll
    for (int i = 0; i < 4; ++i)
      gld_lds16(bk + (size_t)i * 32 * K, bsdst + i * 2048);
    __syncthreads();

    #pragma unroll
    for (int ks = 0; ks < 2; ++ks){
      bf16x8 af[4], bfr[4];
      const int kb = ks * 64 + ((lane >> 4) * 16);
      #pragma unroll
      for (int m = 0; m < 4; ++m)
        af[m] = *(const bf16x8*)((const char*)As + (wr + m * 16 + (lane & 15)) * 128 + kb);
      #pragma unroll
      for (int n = 0; n < 4; ++n)
        bfr[n] = *(const bf16x8*)((const char*)Bs + (wc + n * 16 + (lane & 15)) * 128 + kb);
      #pragma unroll
      for (int m = 0; m < 4; ++m)
        #pragma unroll
        for (int n = 0; n < 4; ++n)
          acc[m][n] = __builtin_amdgcn_mfma_f32_16x16x32_bf16(af[m], bfr[n], acc[m][n], 0, 0, 0);
    }
    __syncthreads();
  }

  #pragma unroll
  for (int m = 0; m < 4; ++m){
    #pragma unroll
    for (int n = 0; n < 4; ++n){
      int col = bcol + wc + n * 16 + (lane & 15);
      #pragma unroll
      for (int j = 0; j < 4; ++j){
        int row = brow + wr + m * 16 + ((lane >> 4) * 4) + j;
        float v = acc[m][n][j];
        if (EPI == 2){
          v = fmaxf(v + bias[col], 0.f);
          obf[(size_t)row * 4608 + 3840 + col] = f2bf(v);
        } else {
          v = fmaxf(v + bias[col], 0.f);
          of32[(size_t)row * 768 + col] = v;
        }
      }
    }
  }
}

// ---------------- per-graph segment sum + build bf16 [h | msg] A-buffer (fallback / layer-0)
__global__ __launch_bounds__(256) void k_scatter(const float* __restrict__ h,
                                                 const int* __restrict__ esrc,
                                                 const int* __restrict__ etgt,
                                                 unsigned short* __restrict__ acat){
  int g = blockIdx.x;
  int t = threadIdx.x;
  __shared__ int cnt[32];
  __shared__ unsigned char lst[32][64];
  if (t < 32) cnt[t] = 0;
  __syncthreads();
  if (t < 64){
    int e = g * 64 + t;
    int src = esrc[e] - g * 32;
    int tgt = etgt[e] - g * 32;
    int slot = atomicAdd(&cnt[tgt], 1);
    lst[tgt][slot] = (unsigned char)src;
  }
  __syncthreads();
  for (int n = 0; n < 32; ++n){
    size_t grow = (size_t)(g * 32 + n);
    const float* hr = h + grow * 768;
    unsigned short* oa = acat + grow * 1536;
    float a0 = 0.f, a1 = 0.f, a2 = 0.f;
    int c = cnt[n];
    for (int e = 0; e < c; ++e){
      const float* rowp = h + (size_t)(g * 32 + lst[n][e]) * 768;
      a0 += rowp[t]; a1 += rowp[t + 256]; a2 += rowp[t + 512];
    }
    oa[t]       = f2bf(hr[t]);
    oa[t + 256] = f2bf(hr[t + 256]);
    oa[t + 512] = f2bf(hr[t + 512]);
    oa[768 + t]       = f2bf(a0);
    oa[768 + t + 256] = f2bf(a1);
    oa[768 + t + 512] = f2bf(a2);
  }
}

// ---------------- per-graph: dist + gather h_c/h_t/h_dist into edge_repr
__global__ __launch_bounds__(256) void k_build(const float* __restrict__ h,
                                               const unsigned short* __restrict__ htext,
                                               const int* __restrict__ tni,
                                               const int* __restrict__ esrc,
                                               const int* __restrict__ etgt,
                                               const float* __restrict__ dist_emb,
                                               unsigned short* __restrict__ er){
  int g = blockIdx.x;
  int t = threadIdx.x;
  __shared__ int s_dist;
  int c = tni[g * 2 + 0], tt = tni[g * 2 + 1];
  if (t == 0){
    // reference quirk: first_edge indexed with LOCAL node ids -> graph 0's edges only
    int cu = c, tu = tt;
    for (int e = 0; e < 64; ++e){ if (esrc[e] == c){ cu = etgt[e]; break; } }
    for (int e = 0; e < 64; ++e){ if (esrc[e] == tt){ tu = etgt[e]; break; } }
    int d = cu - tu; if (d < 0) d = -d; if (d > 31) d = 31;
    s_dist = d;
  }
  __syncthreads();
  size_t rc = (size_t)(g * 32 + c) * 768, rt = (size_t)(g * 32 + tt) * 768;
  unsigned short* o = er + (size_t)g * 4608;
  int d = s_dist;
  for (int i = t; i < 768; i += 256){
    o[i]        = f2bf(h[rc + i]);
    o[768 + i]  = htext[rc + i];
    o[1536 + i] = f2bf(h[rt + i]);
    o[2304 + i] = htext[rt + i];
    o[3072 + i] = f2bf(dist_emb[(size_t)d * 768 + i]);
  }
}

// ---------------- logits: out[i] = hid[i,:] . W_p2 + b_p2
__global__ __launch_bounds__(256) void k_logits(const float* __restrict__ hid,
                                                const float* __restrict__ wp2,
                                                const float* __restrict__ bp2,
                                                float* __restrict__ out){
  int row = blockIdx.x * 4 + (threadIdx.x >> 6);
  int lane = threadIdx.x & 63;
  const float* r = hid + (size_t)row * 768;
  float s = 0.f;
  for (int j = lane; j < 768; j += 64) s += r[j] * wp2[j];
  #pragma unroll
  for (int off = 32; off; off >>= 1) s += __shfl_down(s, off);
  if (lane == 0) out[row] = s + bp2[0];
}

extern "C" void kernel_launch(void* const* d_in, const int* in_sizes, int n_in,
                              void* d_out, int out_size, void* d_ws, size_t ws_size,
                              hipStream_t stream){
  const float* x        = (const float*)d_in[0];
  const int*   sid      = (const int*)d_in[1];
  const int*   eid      = (const int*)d_in[2];
  const int*   esrc     = (const int*)d_in[3];
  const int*   etgt     = esrc + EE;
  const int*   tni      = (const int*)d_in[4];
  const float* expl     = (const float*)d_in[5];
  const float* W_sem    = (const float*)d_in[6];
  const float* spk      = (const float*)d_in[7];
  const float* emo      = (const float*)d_in[8];
  const float* w_self   = (const float*)d_in[9];
  const float* w_nbr    = (const float*)d_in[10];
  const float* dist_emb = (const float*)d_in[11];
  const float* W_expl   = (const float*)d_in[12];
  const float* b_expl   = (const float*)d_in[13];
  const float* W_p1     = (const float*)d_in[14];
  const float* b_p1     = (const float*)d_in[15];
  const float* W_p2     = (const float*)d_in[16];
  const float* b_p2     = (const float*)d_in[17];

  char* ws = (char*)d_ws;
  size_t off = 0;
  auto alloc = [&](size_t bytes) -> void* {
    void* p = ws + off; off += (bytes + 255) & ~(size_t)255; return p;
  };
  float*          h     = (float*)alloc((size_t)NN * HH * 4);
  unsigned short* htext = (unsigned short*)alloc((size_t)NN * HH * 2);
  unsigned short* acatA = (unsigned short*)alloc((size_t)NN * KCAT * 2);
  unsigned short* WsemT = (unsigned short*)alloc((size_t)HH * KSEM * 2);
  unsigned short* WcatT = (unsigned short*)alloc((size_t)3 * HH * KCAT * 2);
  unsigned short* WexplT= (unsigned short*)alloc((size_t)HH * HH * 2);
  unsigned short* Wp1T  = (unsigned short*)alloc((size_t)HH * KP1 * 2);
  unsigned short* erepr = (unsigned short*)alloc((size_t)BB * KP1 * 2);
  float*          hid   = (float*)alloc((size_t)BB * HH * 4);
  unsigned short* explbf= (unsigned short*)alloc((size_t)BB * HH * 2);
  unsigned short* acatB = (unsigned short*)alloc((size_t)NN * KCAT * 2);
  const bool fused = (off <= ws_size);   // ping-pong acat needs +96MB; else fall back
  // xbf aliases acatA: only live until sem GEMM completes; acatA first written after.
  unsigned short* xbf   = acatA;
  (void)in_sizes; (void)n_in; (void)out_size;

  // weight transposes (f32 -> bf16, [K][768] -> [768][K])
  k_transpose<<<dim3(KSEM/32, 24), 256, 0, stream>>>(W_sem, WsemT, KSEM, KSEM, 0);
  for (int l = 0; l < 3; ++l){
    k_transpose<<<dim3(24, 24), 256, 0, stream>>>(w_self + (size_t)l*HH*HH, WcatT + (size_t)l*HH*KCAT, HH, KCAT, 0);
    k_transpose<<<dim3(24, 24), 256, 0, stream>>>(w_nbr  + (size_t)l*HH*HH, WcatT + (size_t)l*HH*KCAT, HH, KCAT, HH);
  }
  k_transpose<<<dim3(24, 24), 256, 0, stream>>>(W_expl, WexplT, HH, HH, 0);
  k_transpose<<<dim3(KP1/32, 24), 256, 0, stream>>>(W_p1, Wp1T, KP1, KP1, 0);

  // activation casts f32 -> bf16
  k_cast<<<(NN*KSEM/8 + 255)/256, 256, 0, stream>>>(x, xbf, NN*KSEM/8);
  k_cast<<<(BB*HH/8 + 255)/256, 256, 0, stream>>>(expl, explbf, BB*HH/8);

  // h_text = relu(x @ W_sem + spk + emo)   [256x128, 768 blocks = 3/CU]
  k_gemm8<0,0><<<6*(NN/256), 512, 0, stream>>>(xbf, WsemT, KSEM,
      h, htext, sid, eid, spk, emo, nullptr, nullptr, nullptr);

  // layer-0 A-buffer from h_text
  k_scatter<<<BB, 256, 0, stream>>>(h, esrc, etgt, acatA);

  if (fused){
    // GNN layers; epilogue of l=0,1 builds the next layer's A-buffer (ping-pong)
    k_gemm8<1,1><<<6*(NN/256), 512, 0, stream>>>(acatA, WcatT + (size_t)0*HH*KCAT, KCAT,
        h, nullptr, nullptr, nullptr, nullptr, nullptr, esrc, etgt, acatB);
    k_gemm8<1,1><<<6*(NN/256), 512, 0, stream>>>(acatB, WcatT + (size_t)1*HH*KCAT, KCAT,
        h, nullptr, nullptr, nullptr, nullptr, nullptr, esrc, etgt, acatA);
    k_gemm8<1,0><<<6*(NN/256), 512, 0, stream>>>(acatA, WcatT + (size_t)2*HH*KCAT, KCAT,
        h, nullptr, nullptr, nullptr, nullptr, nullptr, nullptr, nullptr, nullptr);
  } else {
    for (int l = 0; l < 3; ++l){
      if (l > 0) k_scatter<<<BB, 256, 0, stream>>>(h, esrc, etgt, acatA);
      k_gemm8<1,0><<<6*(NN/256), 512, 0, stream>>>(acatA, WcatT + (size_t)l*HH*KCAT, KCAT,
          h, nullptr, nullptr, nullptr, nullptr, nullptr, nullptr, nullptr, nullptr);
    }
  }

  // z_teacher into edge_repr cols [3840,4608)  [128^2]
  k_gemm<2><<<6*(BB/128), 256, 0, stream>>>(explbf, WexplT, HH, b_expl, erepr, nullptr);

  // gather h_c/h_t/h_dist into edge_repr cols [0,3840)
  k_build<<<BB, 256, 0, stream>>>(h, htext, tni, esrc, etgt, dist_emb, erepr);

  // hid = relu(edge_repr @ W_p1 + b_p1)  [128^2]
  k_gemm<3><<<6*(BB/128), 256, 0, stream>>>(erepr, Wp1T, KP1, b_p1, nullptr, hid);

  // logits
  k_logits<<<BB/4, 256, 0, stream>>>(hid, W_p2, b_p2, (float*)d_out);
}